// Round 8
// baseline (505.263 us; speedup 1.0000x reference)
//
#include <hip/hip_runtime.h>
#include <hip/hip_fp16.h>

#define NN 50000
#define NE 1000000
#define NEP 400000
#define HD 128
#define CD 768
#define NB_SCAN 196  // ceil(NN/256)
#define FSTR 256     // feat row stride (ushorts): [z(128) | c(128)]

typedef _Float16 f16x8 __attribute__((ext_vector_type(8)));
typedef _Float16 f16x2 __attribute__((ext_vector_type(2)));
typedef __fp16 hf16x2 __attribute__((ext_vector_type(2)));
typedef __attribute__((ext_vector_type(4))) float f32x4;

__device__ __forceinline__ unsigned pk2h(float a, float b) {
    hf16x2 p = __builtin_amdgcn_cvt_pkrtz(a, b);
    return __builtin_bit_cast(unsigned, p);
}
__device__ __forceinline__ ushort f2h(float x) {
    return (ushort)(pk2h(x, 0.f) & 0xffffu);
}
__device__ __forceinline__ unsigned h2mul(unsigned a, unsigned b) {
    f16x2 ha = __builtin_bit_cast(f16x2, a);
    f16x2 hb = __builtin_bit_cast(f16x2, b);
    f16x2 r = ha * hb;
    return __builtin_bit_cast(unsigned, r);
}
__device__ __forceinline__ f16x8 pack8h(float4 a0, float4 a1) {
    union { unsigned u[4]; f16x8 v; } r;
    r.u[0] = pk2h(a0.x, a0.y);
    r.u[1] = pk2h(a0.z, a0.w);
    r.u[2] = pk2h(a1.x, a1.y);
    r.u[3] = pk2h(a1.z, a1.w);
    return r.v;
}
__device__ __forceinline__ float2 h2f2(unsigned u) {
    f16x2 h = __builtin_bit_cast(f16x2, u);
    return make_float2((float)h[0], (float)h[1]);
}
__device__ __forceinline__ f16x8 mul8h(uint4 a, uint4 b) {
    union { unsigned u[4]; f16x8 v; } r;
    r.u[0] = h2mul(a.x, b.x);
    r.u[1] = h2mul(a.y, b.y);
    r.u[2] = h2mul(a.z, b.z);
    r.u[3] = h2mul(a.w, b.w);
    return r.v;
}

// ---------------- CSR build ----------------
__global__ __launch_bounds__(256) void count_kernel(const int* __restrict__ col,
                                                    int* __restrict__ cnt) {
    int i = blockIdx.x * 256 + threadIdx.x;
    if (i < NE) atomicAdd(&cnt[col[i]], 1);
}

__global__ __launch_bounds__(256) void dinv_kernel(const int* __restrict__ cnt,
                                                   float* __restrict__ dinv) {
    int i = blockIdx.x * 256 + threadIdx.x;
    if (i < NN) {
        int d = cnt[i];
        dinv[i] = (d > 0) ? 1.0f / sqrtf((float)d) : 0.0f;
    }
}

__global__ __launch_bounds__(256) void scan1_kernel(const int* __restrict__ cnt,
                                                    int* __restrict__ partial,
                                                    int* __restrict__ bsum) {
    __shared__ int s[256];
    int i = blockIdx.x * 256 + threadIdx.x;
    int v = (i < NN) ? cnt[i] : 0;
    s[threadIdx.x] = v;
    __syncthreads();
    for (int o = 1; o < 256; o <<= 1) {
        int t = (threadIdx.x >= o) ? s[threadIdx.x - o] : 0;
        __syncthreads();
        s[threadIdx.x] += t;
        __syncthreads();
    }
    if (i < NN) partial[i] = s[threadIdx.x] - v;
    if (threadIdx.x == 255) bsum[blockIdx.x] = s[255];
}

__global__ __launch_bounds__(256) void scan2_kernel(int* __restrict__ bsum) {
    __shared__ int s[256];
    int v = (threadIdx.x < NB_SCAN) ? bsum[threadIdx.x] : 0;
    s[threadIdx.x] = v;
    __syncthreads();
    for (int o = 1; o < 256; o <<= 1) {
        int t = (threadIdx.x >= o) ? s[threadIdx.x - o] : 0;
        __syncthreads();
        s[threadIdx.x] += t;
        __syncthreads();
    }
    if (threadIdx.x < NB_SCAN) bsum[threadIdx.x] = s[threadIdx.x] - v;
}

__global__ __launch_bounds__(256) void scan3_kernel(const int* __restrict__ partial,
                                                    const int* __restrict__ bsum,
                                                    int* __restrict__ off,
                                                    int* __restrict__ cursor) {
    int i = blockIdx.x * 256 + threadIdx.x;
    if (i < NN) {
        int o = partial[i] + bsum[blockIdx.x];
        off[i] = o;
        cursor[i] = o;
    }
}

__global__ __launch_bounds__(256) void fill_kernel(const int* __restrict__ row,
                                                   const int* __restrict__ col,
                                                   const float* __restrict__ dinv,
                                                   int* __restrict__ cursor,
                                                   int* __restrict__ csr_idx,
                                                   float* __restrict__ csr_w) {
    int e = blockIdx.x * 256 + threadIdx.x;
    if (e < NE) {
        int c = col[e], r = row[e];
        int slot = atomicAdd(&cursor[c], 1);
        csr_idx[slot] = r;
        csr_w[slot] = dinv[r];
    }
}

// ---------------- W(K x 128) -> MFMA B-fragment order, f16 ----------------
// wf[((ks*8+nt)*64 + l)*8 + j] = W[ks*32 + (l>>4)*8 + j][nt*16 + (l&15)]
__global__ __launch_bounds__(256) void wfrag_kernel(const float* __restrict__ w,
                                                    ushort* __restrict__ wf) {
    int tid = blockIdx.x * 256 + threadIdx.x;
    int ks = tid >> 9, nt = (tid >> 6) & 7, l = tid & 63;
    int kbase = ks * 32 + ((l >> 4) << 3);
    int colq = nt * 16 + (l & 15);
    ushort r[8];
#pragma unroll
    for (int j = 0; j < 8; ++j) r[j] = f2h(w[(size_t)(kbase + j) * HD + colq]);
    *(uint4*)&wf[(size_t)tid * 8] = *(uint4*)r;
}

// ---------------- MFMA matmul: out(NN x 128) = f16(A(NN x KS*32)) @ Wfrag, optional chem epilogue ----------------
template <int KS, bool EPI>
__global__ __launch_bounds__(256) void feat_mfma_kernel(const float* __restrict__ A,
                                                        const ushort* __restrict__ wf,
                                                        const float* __restrict__ bias,
                                                        const float* __restrict__ mask,
                                                        ushort* __restrict__ out,
                                                        int ostride, int ooff) {
    __shared__ float At[64][36];
    const int t = threadIdx.x;
    const int w = t >> 6, lane = t & 63;
    const int rowBase = blockIdx.x * 64;
    const int nt0 = w * 2;
    const int K = KS * 32;

    f32x4 acc[4][2] = {};

    for (int ks = 0; ks < KS; ++ks) {
        __syncthreads();
#pragma unroll
        for (int i = 0; i < 2; ++i) {
            int li = t + i * 256;           // [0,512) float4 tasks
            int r = li >> 3, c4 = li & 7;   // row, float4-col
            int grow = rowBase + r;
            float4 v = make_float4(0.f, 0.f, 0.f, 0.f);
            if (grow < NN) v = *(const float4*)&A[(size_t)grow * K + ks * 32 + c4 * 4];
            *(float4*)&At[r][c4 * 4] = v;
        }
        __syncthreads();
        f16x8 bf0 = ((const f16x8*)wf)[(ks * 8 + nt0) * 64 + lane];
        f16x8 bf1 = ((const f16x8*)wf)[(ks * 8 + nt0 + 1) * 64 + lane];
#pragma unroll
        for (int mt = 0; mt < 4; ++mt) {
            int row = mt * 16 + (lane & 15);
            float4 a0 = *(const float4*)&At[row][(lane >> 4) * 8];
            float4 a1 = *(const float4*)&At[row][(lane >> 4) * 8 + 4];
            f16x8 af = pack8h(a0, a1);
            acc[mt][0] = __builtin_amdgcn_mfma_f32_16x16x32_f16(af, bf0, acc[mt][0], 0, 0, 0);
            acc[mt][1] = __builtin_amdgcn_mfma_f32_16x16x32_f16(af, bf1, acc[mt][1], 0, 0, 0);
        }
    }

    const int c0 = lane & 15, rq = lane >> 4;
    float bb0 = EPI ? bias[nt0 * 16 + c0] : 0.f;
    float bb1 = EPI ? bias[nt0 * 16 + 16 + c0] : 0.f;
#pragma unroll
    for (int mt = 0; mt < 4; ++mt) {
#pragma unroll
        for (int reg = 0; reg < 4; ++reg) {
            int grow = rowBase + mt * 16 + rq * 4 + reg;
            if (grow < NN) {
                float v0 = acc[mt][0][reg], v1 = acc[mt][1][reg];
                if (EPI) {
                    float m = mask[grow];
                    v0 = fmaxf(v0 + bb0, 0.f) * m;
                    v1 = fmaxf(v1 + bb1, 0.f) * m;
                }
                out[(size_t)grow * ostride + ooff + nt0 * 16 + c0] = f2h(v0);
                out[(size_t)grow * ostride + ooff + nt0 * 16 + 16 + c0] = f2h(v1);
            }
        }
    }
}

// ---------------- CSR pull aggregation (f16 h), fused bias+relu+dinv scale ----------------
template <bool F16OUT>
__global__ __launch_bounds__(256) void gather_kernel(const int* __restrict__ off,
                                                     const int* __restrict__ cnt,
                                                     const int* __restrict__ csr_idx,
                                                     const float* __restrict__ csr_w,
                                                     const float* __restrict__ dinv,
                                                     const ushort* __restrict__ h,
                                                     const float* __restrict__ bias,
                                                     float* __restrict__ z,
                                                     ushort* __restrict__ zb,
                                                     int ostride) {
    int v = blockIdx.x * 4 + (threadIdx.x >> 6);
    if (v >= NN) return;
    int lane = threadIdx.x & 63;
    int s = off[v];
    int e = s + cnt[v];
    float accx = 0.f, accy = 0.f;
    for (; s + 3 < e; s += 4) {
        int r0 = csr_idx[s], r1 = csr_idx[s + 1], r2 = csr_idx[s + 2], r3 = csr_idx[s + 3];
        float w0 = csr_w[s], w1 = csr_w[s + 1], w2 = csr_w[s + 2], w3 = csr_w[s + 3];
        unsigned u0 = *(const unsigned*)&h[(size_t)r0 * HD + lane * 2];
        unsigned u1 = *(const unsigned*)&h[(size_t)r1 * HD + lane * 2];
        unsigned u2 = *(const unsigned*)&h[(size_t)r2 * HD + lane * 2];
        unsigned u3 = *(const unsigned*)&h[(size_t)r3 * HD + lane * 2];
        float2 f0 = h2f2(u0), f1 = h2f2(u1), f2 = h2f2(u2), f3 = h2f2(u3);
        accx = fmaf(f0.x, w0, accx); accy = fmaf(f0.y, w0, accy);
        accx = fmaf(f1.x, w1, accx); accy = fmaf(f1.y, w1, accy);
        accx = fmaf(f2.x, w2, accx); accy = fmaf(f2.y, w2, accy);
        accx = fmaf(f3.x, w3, accx); accy = fmaf(f3.y, w3, accy);
    }
    for (; s < e; ++s) {
        int r0 = csr_idx[s];
        float w0 = csr_w[s];
        float2 f0 = h2f2(*(const unsigned*)&h[(size_t)r0 * HD + lane * 2]);
        accx = fmaf(f0.x, w0, accx); accy = fmaf(f0.y, w0, accy);
    }
    float dv = dinv[v];
    float2 b = *(const float2*)&bias[lane * 2];
    float ox = fmaxf(fmaf(accx, dv, b.x), 0.f);
    float oy = fmaxf(fmaf(accy, dv, b.y), 0.f);
    if (F16OUT) {
        *(unsigned*)&zb[(size_t)v * ostride + lane * 2] = pk2h(ox, oy);
    } else {
        float2 o; o.x = ox; o.y = oy;
        *(float2*)&z[(size_t)v * HD + lane * 2] = o;
    }
}

// ---------------- decoder: f16 MFMA, no LDS, no barriers ----------------
// block = 64 edges, 4 waves; wave w owns edges w*16..w*16+15 and all 8 nt.
// A-frag gathered directly from feat: lane holds A[row=lane&15][k=(lane>>4)*8+j].
__global__ __launch_bounds__(256, 6) void decode_mfma_kernel(const int* __restrict__ pos_edge,
                                                             const int* __restrict__ neg_edge,
                                                             const ushort* __restrict__ feat,
                                                             const ushort* __restrict__ w1f,
                                                             const float* __restrict__ b1,
                                                             const float* __restrict__ w2,
                                                             const float* __restrict__ b2,
                                                             float* __restrict__ out) {
    const int t = threadIdx.x;
    const int w = t >> 6, lane = t & 63;
    const int bid = blockIdx.x;
    const bool isPos = bid < (NEP / 64);
    const int* edges = isPos ? pos_edge : neg_edge;
    const int ebase = (isPos ? bid : bid - NEP / 64) * 64;
    float* op = out + (isPos ? 0 : NEP);

    const int e = w * 16 + (lane & 15);   // edge within block
    const int seg = lane >> 4;            // k-octet within 32-k chunk
    const int eg = ebase + e;
    const int s = edges[2 * eg];
    const int dd = edges[2 * eg + 1];
    const ushort* sp = feat + (size_t)s * FSTR + seg * 8;
    const ushort* dp = feat + (size_t)dd * FSTR + seg * 8;

    f32x4 acc[8] = {};
#pragma unroll
    for (int ks = 0; ks < 8; ++ks) {
        uint4 av = *(const uint4*)(sp + ks * 32);
        uint4 bv = *(const uint4*)(dp + ks * 32);
        f16x8 af = mul8h(av, bv);
#pragma unroll
        for (int nt = 0; nt < 8; ++nt) {
            f16x8 bf = ((const f16x8*)w1f)[(ks * 8 + nt) * 64 + lane];
            acc[nt] = __builtin_amdgcn_mfma_f32_16x16x32_f16(af, bf, acc[nt], 0, 0, 0);
        }
    }

    // epilogue: D[row=edge=(lane>>4)*4+reg][col=nt*16+(lane&15)]
    const int c0 = lane & 15, rq = lane >> 4;
    float p[4] = {0.f, 0.f, 0.f, 0.f};
#pragma unroll
    for (int nt = 0; nt < 8; ++nt) {
        float b1v = b1[nt * 16 + c0];
        float w2v = w2[nt * 16 + c0];
#pragma unroll
        for (int reg = 0; reg < 4; ++reg) {
            float h = fmaxf(acc[nt][reg] + b1v, 0.f);
            p[reg] = fmaf(h, w2v, p[reg]);
        }
    }
    float b2v = b2[0];
#pragma unroll
    for (int reg = 0; reg < 4; ++reg) {
        float v = p[reg];
        v += __shfl_xor(v, 1);
        v += __shfl_xor(v, 2);
        v += __shfl_xor(v, 4);
        v += __shfl_xor(v, 8);
        if (c0 == 0) op[ebase + w * 16 + rq * 4 + reg] = v + b2v;
    }
}

extern "C" void kernel_launch(void* const* d_in, const int* in_sizes, int n_in,
                              void* d_out, int out_size, void* d_ws, size_t ws_size,
                              hipStream_t stream) {
    const int* edge_index = (const int*)d_in[0];
    const float* chemistry = (const float*)d_in[1];
    const int* pos_edge = (const int*)d_in[2];
    const int* neg_edge = (const int*)d_in[3];
    const float* smiles_mask = (const float*)d_in[4];
    const float* node_emb = (const float*)d_in[5];
    const float* conv_w = (const float*)d_in[6];
    const float* conv_b = (const float*)d_in[7];
    const float* chem_w = (const float*)d_in[8];
    const float* chem_b = (const float*)d_in[9];
    const float* dec_w1 = (const float*)d_in[10];
    const float* dec_b1 = (const float*)d_in[11];
    const float* dec_w2 = (const float*)d_in[12];
    const float* dec_b2 = (const float*)d_in[13];
    float* out = (float*)d_out;

    char* ws = (char*)d_ws;
    int* cnt = (int*)(ws + 0);
    float* dinv = (float*)(ws + 204800);
    int* partial = (int*)(ws + 409600);
    int* off = (int*)(ws + 614400);
    int* cursor = (int*)(ws + 819200);
    int* bsum = (int*)(ws + 1024000);
    int* csr_idx = (int*)(ws + 1048576);     // 4 MB
    float* csr_w = (float*)(ws + 5242880);   // 4 MB
    float* bufZ = (float*)(ws + 9437184);    // 25.6 MB (fp32 z, layer-0 out)
    ushort* hb = (ushort*)(ws + 35037184);   // 12.8 MB
    ushort* feat = (ushort*)(ws + 47837184); // 25.6 MB  [z | c] interleaved
    ushort* w1f = (ushort*)(ws + 73437184);  // 64 KB
    ushort* wcf = (ushort*)(ws + 73502720);  // 192 KB
    ushort* wc0f = (ushort*)(ws + 73699328); // 32 KB
    ushort* wc1f = (ushort*)(ws + 73732096); // 32 KB

    const int* e_row = edge_index;
    const int* e_col = edge_index + NE;

    // ---- CSR build + weight fragment packs ----
    hipMemsetAsync(cnt, 0, (size_t)NN * 4, stream);
    count_kernel<<<(NE + 255) / 256, 256, 0, stream>>>(e_col, cnt);
    dinv_kernel<<<(NN + 255) / 256, 256, 0, stream>>>(cnt, dinv);
    scan1_kernel<<<NB_SCAN, 256, 0, stream>>>(cnt, partial, bsum);
    scan2_kernel<<<1, 256, 0, stream>>>(bsum);
    scan3_kernel<<<NB_SCAN, 256, 0, stream>>>(partial, bsum, off, cursor);
    fill_kernel<<<(NE + 255) / 256, 256, 0, stream>>>(e_row, e_col, dinv, cursor, csr_idx, csr_w);
    wfrag_kernel<<<16, 256, 0, stream>>>(dec_w1, w1f);             // 8 ks
    wfrag_kernel<<<48, 256, 0, stream>>>(chem_w, wcf);             // 24 ks
    wfrag_kernel<<<8, 256, 0, stream>>>(conv_w, wc0f);             // 4 ks
    wfrag_kernel<<<8, 256, 0, stream>>>(conv_w + HD * HD, wc1f);   // 4 ks

    const int mmGrid = (NN + 63) / 64;
    const int gaGrid = (NN + 3) / 4;

    // layer 0: h = node_emb @ W0 (MFMA), then aggregate -> fp32 z
    feat_mfma_kernel<4, false><<<mmGrid, 256, 0, stream>>>(node_emb, wc0f, nullptr, nullptr, hb, HD, 0);
    gather_kernel<false><<<gaGrid, 256, 0, stream>>>(off, cnt, csr_idx, csr_w, dinv, hb, conv_b, bufZ, nullptr, 0);

    // layer 1: h = z @ W1 (MFMA), aggregate -> f16 z into feat[:,0:128]
    feat_mfma_kernel<4, false><<<mmGrid, 256, 0, stream>>>(bufZ, wc1f, nullptr, nullptr, hb, HD, 0);
    gather_kernel<true><<<gaGrid, 256, 0, stream>>>(off, cnt, csr_idx, csr_w, dinv, hb, conv_b + HD, nullptr, feat, FSTR);

    // chemistry features -> feat[:,128:256]
    feat_mfma_kernel<24, true><<<mmGrid, 256, 0, stream>>>(chemistry, wcf, chem_b, smiles_mask, feat, FSTR, HD);

    // decode pos+neg fused
    decode_mfma_kernel<<<2 * (NEP / 64), 256, 0, stream>>>(pos_edge, neg_edge, feat, w1f,
                                                           dec_b1, dec_w2, dec_b2, out);
}

// Round 9
// 476.181 us; speedup vs baseline: 1.0611x; 1.0611x over previous
//
#include <hip/hip_runtime.h>
#include <hip/hip_fp16.h>

#define NN 50000
#define NE 1000000
#define NEP 400000
#define HD 128
#define CD 768
#define NB_SCAN 196  // ceil(NN/256)
#define FSTR 256     // feat row stride (ushorts): [z(128) | c(128)]

typedef _Float16 f16x8 __attribute__((ext_vector_type(8)));
typedef _Float16 f16x2 __attribute__((ext_vector_type(2)));
typedef __fp16 hf16x2 __attribute__((ext_vector_type(2)));
typedef __attribute__((ext_vector_type(4))) float f32x4;

__device__ __forceinline__ unsigned pk2h(float a, float b) {
    hf16x2 p = __builtin_amdgcn_cvt_pkrtz(a, b);
    return __builtin_bit_cast(unsigned, p);
}
__device__ __forceinline__ ushort f2h(float x) {
    return (ushort)(pk2h(x, 0.f) & 0xffffu);
}
__device__ __forceinline__ unsigned h2mul(unsigned a, unsigned b) {
    f16x2 ha = __builtin_bit_cast(f16x2, a);
    f16x2 hb = __builtin_bit_cast(f16x2, b);
    f16x2 r = ha * hb;
    return __builtin_bit_cast(unsigned, r);
}
__device__ __forceinline__ f16x8 pack8h(float4 a0, float4 a1) {
    union { unsigned u[4]; f16x8 v; } r;
    r.u[0] = pk2h(a0.x, a0.y);
    r.u[1] = pk2h(a0.z, a0.w);
    r.u[2] = pk2h(a1.x, a1.y);
    r.u[3] = pk2h(a1.z, a1.w);
    return r.v;
}
__device__ __forceinline__ float2 h2f2(unsigned u) {
    f16x2 h = __builtin_bit_cast(f16x2, u);
    return make_float2((float)h[0], (float)h[1]);
}
__device__ __forceinline__ f16x8 mul8h(uint4 a, uint4 b) {
    union { unsigned u[4]; f16x8 v; } r;
    r.u[0] = h2mul(a.x, b.x);
    r.u[1] = h2mul(a.y, b.y);
    r.u[2] = h2mul(a.z, b.z);
    r.u[3] = h2mul(a.w, b.w);
    return r.v;
}

// ---------------- CSR build ----------------
__global__ __launch_bounds__(256) void count_kernel(const int* __restrict__ col,
                                                    int* __restrict__ cnt) {
    int i = blockIdx.x * 256 + threadIdx.x;
    if (i < NE) atomicAdd(&cnt[col[i]], 1);
}

__global__ __launch_bounds__(256) void dinv_kernel(const int* __restrict__ cnt,
                                                   float* __restrict__ dinv) {
    int i = blockIdx.x * 256 + threadIdx.x;
    if (i < NN) {
        int d = cnt[i];
        dinv[i] = (d > 0) ? 1.0f / sqrtf((float)d) : 0.0f;
    }
}

__global__ __launch_bounds__(256) void scan1_kernel(const int* __restrict__ cnt,
                                                    int* __restrict__ partial,
                                                    int* __restrict__ bsum) {
    __shared__ int s[256];
    int i = blockIdx.x * 256 + threadIdx.x;
    int v = (i < NN) ? cnt[i] : 0;
    s[threadIdx.x] = v;
    __syncthreads();
    for (int o = 1; o < 256; o <<= 1) {
        int t = (threadIdx.x >= o) ? s[threadIdx.x - o] : 0;
        __syncthreads();
        s[threadIdx.x] += t;
        __syncthreads();
    }
    if (i < NN) partial[i] = s[threadIdx.x] - v;
    if (threadIdx.x == 255) bsum[blockIdx.x] = s[255];
}

__global__ __launch_bounds__(256) void scan2_kernel(int* __restrict__ bsum) {
    __shared__ int s[256];
    int v = (threadIdx.x < NB_SCAN) ? bsum[threadIdx.x] : 0;
    s[threadIdx.x] = v;
    __syncthreads();
    for (int o = 1; o < 256; o <<= 1) {
        int t = (threadIdx.x >= o) ? s[threadIdx.x - o] : 0;
        __syncthreads();
        s[threadIdx.x] += t;
        __syncthreads();
    }
    if (threadIdx.x < NB_SCAN) bsum[threadIdx.x] = s[threadIdx.x] - v;
}

__global__ __launch_bounds__(256) void scan3_kernel(const int* __restrict__ partial,
                                                    const int* __restrict__ bsum,
                                                    int* __restrict__ off,
                                                    int* __restrict__ cursor) {
    int i = blockIdx.x * 256 + threadIdx.x;
    if (i < NN) {
        int o = partial[i] + bsum[blockIdx.x];
        off[i] = o;
        cursor[i] = o;
    }
}

__global__ __launch_bounds__(256) void fill_kernel(const int* __restrict__ row,
                                                   const int* __restrict__ col,
                                                   const float* __restrict__ dinv,
                                                   int* __restrict__ cursor,
                                                   int* __restrict__ csr_idx,
                                                   float* __restrict__ csr_w) {
    int e = blockIdx.x * 256 + threadIdx.x;
    if (e < NE) {
        int c = col[e], r = row[e];
        int slot = atomicAdd(&cursor[c], 1);
        csr_idx[slot] = r;
        csr_w[slot] = dinv[r];
    }
}

// ---------------- W(K x 128) -> MFMA B-fragment order, f16 ----------------
// wf[((ks*8+nt)*64 + l)*8 + j] = W[ks*32 + (l>>4)*8 + j][nt*16 + (l&15)]
__global__ __launch_bounds__(256) void wfrag_kernel(const float* __restrict__ w,
                                                    ushort* __restrict__ wf) {
    int tid = blockIdx.x * 256 + threadIdx.x;
    int ks = tid >> 9, nt = (tid >> 6) & 7, l = tid & 63;
    int kbase = ks * 32 + ((l >> 4) << 3);
    int colq = nt * 16 + (l & 15);
    ushort r[8];
#pragma unroll
    for (int j = 0; j < 8; ++j) r[j] = f2h(w[(size_t)(kbase + j) * HD + colq]);
    *(uint4*)&wf[(size_t)tid * 8] = *(uint4*)r;
}

// ---------------- MFMA matmul: out(NN x 128) = f16(A(NN x KS*32)) @ Wfrag, optional chem epilogue ----------------
template <int KS, bool EPI>
__global__ __launch_bounds__(256) void feat_mfma_kernel(const float* __restrict__ A,
                                                        const ushort* __restrict__ wf,
                                                        const float* __restrict__ bias,
                                                        const float* __restrict__ mask,
                                                        ushort* __restrict__ out,
                                                        int ostride, int ooff) {
    __shared__ float At[64][36];
    const int t = threadIdx.x;
    const int w = t >> 6, lane = t & 63;
    const int rowBase = blockIdx.x * 64;
    const int nt0 = w * 2;
    const int K = KS * 32;

    f32x4 acc[4][2] = {};

    for (int ks = 0; ks < KS; ++ks) {
        __syncthreads();
#pragma unroll
        for (int i = 0; i < 2; ++i) {
            int li = t + i * 256;           // [0,512) float4 tasks
            int r = li >> 3, c4 = li & 7;   // row, float4-col
            int grow = rowBase + r;
            float4 v = make_float4(0.f, 0.f, 0.f, 0.f);
            if (grow < NN) v = *(const float4*)&A[(size_t)grow * K + ks * 32 + c4 * 4];
            *(float4*)&At[r][c4 * 4] = v;
        }
        __syncthreads();
        f16x8 bf0 = ((const f16x8*)wf)[(ks * 8 + nt0) * 64 + lane];
        f16x8 bf1 = ((const f16x8*)wf)[(ks * 8 + nt0 + 1) * 64 + lane];
#pragma unroll
        for (int mt = 0; mt < 4; ++mt) {
            int row = mt * 16 + (lane & 15);
            float4 a0 = *(const float4*)&At[row][(lane >> 4) * 8];
            float4 a1 = *(const float4*)&At[row][(lane >> 4) * 8 + 4];
            f16x8 af = pack8h(a0, a1);
            acc[mt][0] = __builtin_amdgcn_mfma_f32_16x16x32_f16(af, bf0, acc[mt][0], 0, 0, 0);
            acc[mt][1] = __builtin_amdgcn_mfma_f32_16x16x32_f16(af, bf1, acc[mt][1], 0, 0, 0);
        }
    }

    const int c0 = lane & 15, rq = lane >> 4;
    float bb0 = EPI ? bias[nt0 * 16 + c0] : 0.f;
    float bb1 = EPI ? bias[nt0 * 16 + 16 + c0] : 0.f;
#pragma unroll
    for (int mt = 0; mt < 4; ++mt) {
#pragma unroll
        for (int reg = 0; reg < 4; ++reg) {
            int grow = rowBase + mt * 16 + rq * 4 + reg;
            if (grow < NN) {
                float v0 = acc[mt][0][reg], v1 = acc[mt][1][reg];
                if (EPI) {
                    float m = mask[grow];
                    v0 = fmaxf(v0 + bb0, 0.f) * m;
                    v1 = fmaxf(v1 + bb1, 0.f) * m;
                }
                out[(size_t)grow * ostride + ooff + nt0 * 16 + c0] = f2h(v0);
                out[(size_t)grow * ostride + ooff + nt0 * 16 + 16 + c0] = f2h(v1);
            }
        }
    }
}

// ---------------- CSR pull aggregation (f16 h), fused bias+relu+dinv scale ----------------
template <bool F16OUT>
__global__ __launch_bounds__(256) void gather_kernel(const int* __restrict__ off,
                                                     const int* __restrict__ cnt,
                                                     const int* __restrict__ csr_idx,
                                                     const float* __restrict__ csr_w,
                                                     const float* __restrict__ dinv,
                                                     const ushort* __restrict__ h,
                                                     const float* __restrict__ bias,
                                                     float* __restrict__ z,
                                                     ushort* __restrict__ zb,
                                                     int ostride) {
    int v = blockIdx.x * 4 + (threadIdx.x >> 6);
    if (v >= NN) return;
    int lane = threadIdx.x & 63;
    int s = off[v];
    int e = s + cnt[v];
    float accx = 0.f, accy = 0.f;
    // unroll 8 rows: 8 idx + 8 w + 8 row loads in flight
    for (; s + 7 < e; s += 8) {
        int r0 = csr_idx[s], r1 = csr_idx[s + 1], r2 = csr_idx[s + 2], r3 = csr_idx[s + 3];
        int r4 = csr_idx[s + 4], r5 = csr_idx[s + 5], r6 = csr_idx[s + 6], r7 = csr_idx[s + 7];
        unsigned u0 = *(const unsigned*)&h[(size_t)r0 * HD + lane * 2];
        unsigned u1 = *(const unsigned*)&h[(size_t)r1 * HD + lane * 2];
        unsigned u2 = *(const unsigned*)&h[(size_t)r2 * HD + lane * 2];
        unsigned u3 = *(const unsigned*)&h[(size_t)r3 * HD + lane * 2];
        unsigned u4 = *(const unsigned*)&h[(size_t)r4 * HD + lane * 2];
        unsigned u5 = *(const unsigned*)&h[(size_t)r5 * HD + lane * 2];
        unsigned u6 = *(const unsigned*)&h[(size_t)r6 * HD + lane * 2];
        unsigned u7 = *(const unsigned*)&h[(size_t)r7 * HD + lane * 2];
        float w0 = csr_w[s], w1 = csr_w[s + 1], w2 = csr_w[s + 2], w3 = csr_w[s + 3];
        float w4 = csr_w[s + 4], w5 = csr_w[s + 5], w6 = csr_w[s + 6], w7 = csr_w[s + 7];
        float2 f0 = h2f2(u0), f1 = h2f2(u1), f2 = h2f2(u2), f3 = h2f2(u3);
        float2 f4 = h2f2(u4), f5 = h2f2(u5), f6 = h2f2(u6), f7 = h2f2(u7);
        accx = fmaf(f0.x, w0, accx); accy = fmaf(f0.y, w0, accy);
        accx = fmaf(f1.x, w1, accx); accy = fmaf(f1.y, w1, accy);
        accx = fmaf(f2.x, w2, accx); accy = fmaf(f2.y, w2, accy);
        accx = fmaf(f3.x, w3, accx); accy = fmaf(f3.y, w3, accy);
        accx = fmaf(f4.x, w4, accx); accy = fmaf(f4.y, w4, accy);
        accx = fmaf(f5.x, w5, accx); accy = fmaf(f5.y, w5, accy);
        accx = fmaf(f6.x, w6, accx); accy = fmaf(f6.y, w6, accy);
        accx = fmaf(f7.x, w7, accx); accy = fmaf(f7.y, w7, accy);
    }
    for (; s < e; ++s) {
        int r0 = csr_idx[s];
        float w0 = csr_w[s];
        float2 f0 = h2f2(*(const unsigned*)&h[(size_t)r0 * HD + lane * 2]);
        accx = fmaf(f0.x, w0, accx); accy = fmaf(f0.y, w0, accy);
    }
    float dv = dinv[v];
    float2 b = *(const float2*)&bias[lane * 2];
    float ox = fmaxf(fmaf(accx, dv, b.x), 0.f);
    float oy = fmaxf(fmaf(accy, dv, b.y), 0.f);
    if (F16OUT) {
        *(unsigned*)&zb[(size_t)v * ostride + lane * 2] = pk2h(ox, oy);
    } else {
        float2 o; o.x = ox; o.y = oy;
        *(float2*)&z[(size_t)v * HD + lane * 2] = o;
    }
}

// ---------------- decoder: f16 MFMA, no LDS, no barriers, batched loads ----------------
// block = 64 edges, 4 waves; wave w owns edges w*16..w*16+15 and all 8 nt.
// A-frag gathered directly from feat: lane holds A[row=lane&15][k=(lane>>4)*8+j].
// All 16 row-segment loads issued into registers before any MFMA (MLP depth 16).
__global__ __launch_bounds__(256, 4) void decode_mfma_kernel(const int* __restrict__ pos_edge,
                                                             const int* __restrict__ neg_edge,
                                                             const ushort* __restrict__ feat,
                                                             const ushort* __restrict__ w1f,
                                                             const float* __restrict__ b1,
                                                             const float* __restrict__ w2,
                                                             const float* __restrict__ b2,
                                                             float* __restrict__ out) {
    const int t = threadIdx.x;
    const int w = t >> 6, lane = t & 63;
    const int bid = blockIdx.x;
    const bool isPos = bid < (NEP / 64);
    const int* edges = isPos ? pos_edge : neg_edge;
    const int ebase = (isPos ? bid : bid - NEP / 64) * 64;
    float* op = out + (isPos ? 0 : NEP);

    const int e = w * 16 + (lane & 15);   // edge within block
    const int seg = lane >> 4;            // k-octet within 32-k chunk
    const int eg = ebase + e;
    const int s = edges[2 * eg];
    const int dd = edges[2 * eg + 1];
    const ushort* sp = feat + (size_t)s * FSTR + seg * 8;
    const ushort* dp = feat + (size_t)dd * FSTR + seg * 8;

    uint4 avr[8], bvr[8];
#pragma unroll
    for (int ks = 0; ks < 8; ++ks) avr[ks] = *(const uint4*)(sp + ks * 32);
#pragma unroll
    for (int ks = 0; ks < 8; ++ks) bvr[ks] = *(const uint4*)(dp + ks * 32);

    f32x4 acc[8] = {};
#pragma unroll
    for (int ks = 0; ks < 8; ++ks) {
        f16x8 af = mul8h(avr[ks], bvr[ks]);
#pragma unroll
        for (int nt = 0; nt < 8; ++nt) {
            f16x8 bf = ((const f16x8*)w1f)[(ks * 8 + nt) * 64 + lane];
            acc[nt] = __builtin_amdgcn_mfma_f32_16x16x32_f16(af, bf, acc[nt], 0, 0, 0);
        }
    }

    // epilogue: D[row=edge=(lane>>4)*4+reg][col=nt*16+(lane&15)]
    const int c0 = lane & 15, rq = lane >> 4;
    float p[4] = {0.f, 0.f, 0.f, 0.f};
#pragma unroll
    for (int nt = 0; nt < 8; ++nt) {
        float b1v = b1[nt * 16 + c0];
        float w2v = w2[nt * 16 + c0];
#pragma unroll
        for (int reg = 0; reg < 4; ++reg) {
            float h = fmaxf(acc[nt][reg] + b1v, 0.f);
            p[reg] = fmaf(h, w2v, p[reg]);
        }
    }
    float b2v = b2[0];
#pragma unroll
    for (int reg = 0; reg < 4; ++reg) {
        float v = p[reg];
        v += __shfl_xor(v, 1);
        v += __shfl_xor(v, 2);
        v += __shfl_xor(v, 4);
        v += __shfl_xor(v, 8);
        if (c0 == 0) op[ebase + w * 16 + rq * 4 + reg] = v + b2v;
    }
}

extern "C" void kernel_launch(void* const* d_in, const int* in_sizes, int n_in,
                              void* d_out, int out_size, void* d_ws, size_t ws_size,
                              hipStream_t stream) {
    const int* edge_index = (const int*)d_in[0];
    const float* chemistry = (const float*)d_in[1];
    const int* pos_edge = (const int*)d_in[2];
    const int* neg_edge = (const int*)d_in[3];
    const float* smiles_mask = (const float*)d_in[4];
    const float* node_emb = (const float*)d_in[5];
    const float* conv_w = (const float*)d_in[6];
    const float* conv_b = (const float*)d_in[7];
    const float* chem_w = (const float*)d_in[8];
    const float* chem_b = (const float*)d_in[9];
    const float* dec_w1 = (const float*)d_in[10];
    const float* dec_b1 = (const float*)d_in[11];
    const float* dec_w2 = (const float*)d_in[12];
    const float* dec_b2 = (const float*)d_in[13];
    float* out = (float*)d_out;

    char* ws = (char*)d_ws;
    int* cnt = (int*)(ws + 0);
    float* dinv = (float*)(ws + 204800);
    int* partial = (int*)(ws + 409600);
    int* off = (int*)(ws + 614400);
    int* cursor = (int*)(ws + 819200);
    int* bsum = (int*)(ws + 1024000);
    int* csr_idx = (int*)(ws + 1048576);     // 4 MB
    float* csr_w = (float*)(ws + 5242880);   // 4 MB
    float* bufZ = (float*)(ws + 9437184);    // 25.6 MB (fp32 z, layer-0 out)
    ushort* hb = (ushort*)(ws + 35037184);   // 12.8 MB
    ushort* feat = (ushort*)(ws + 47837184); // 25.6 MB  [z | c] interleaved
    ushort* w1f = (ushort*)(ws + 73437184);  // 64 KB
    ushort* wcf = (ushort*)(ws + 73502720);  // 192 KB
    ushort* wc0f = (ushort*)(ws + 73699328); // 32 KB
    ushort* wc1f = (ushort*)(ws + 73732096); // 32 KB

    const int* e_row = edge_index;
    const int* e_col = edge_index + NE;

    // ---- CSR build + weight fragment packs ----
    hipMemsetAsync(cnt, 0, (size_t)NN * 4, stream);
    count_kernel<<<(NE + 255) / 256, 256, 0, stream>>>(e_col, cnt);
    dinv_kernel<<<(NN + 255) / 256, 256, 0, stream>>>(cnt, dinv);
    scan1_kernel<<<NB_SCAN, 256, 0, stream>>>(cnt, partial, bsum);
    scan2_kernel<<<1, 256, 0, stream>>>(bsum);
    scan3_kernel<<<NB_SCAN, 256, 0, stream>>>(partial, bsum, off, cursor);
    fill_kernel<<<(NE + 255) / 256, 256, 0, stream>>>(e_row, e_col, dinv, cursor, csr_idx, csr_w);
    wfrag_kernel<<<16, 256, 0, stream>>>(dec_w1, w1f);             // 8 ks
    wfrag_kernel<<<48, 256, 0, stream>>>(chem_w, wcf);             // 24 ks
    wfrag_kernel<<<8, 256, 0, stream>>>(conv_w, wc0f);             // 4 ks
    wfrag_kernel<<<8, 256, 0, stream>>>(conv_w + HD * HD, wc1f);   // 4 ks

    const int mmGrid = (NN + 63) / 64;
    const int gaGrid = (NN + 3) / 4;

    // layer 0: h = node_emb @ W0 (MFMA), then aggregate -> fp32 z
    feat_mfma_kernel<4, false><<<mmGrid, 256, 0, stream>>>(node_emb, wc0f, nullptr, nullptr, hb, HD, 0);
    gather_kernel<false><<<gaGrid, 256, 0, stream>>>(off, cnt, csr_idx, csr_w, dinv, hb, conv_b, bufZ, nullptr, 0);

    // layer 1: h = z @ W1 (MFMA), aggregate -> f16 z into feat[:,0:128]
    feat_mfma_kernel<4, false><<<mmGrid, 256, 0, stream>>>(bufZ, wc1f, nullptr, nullptr, hb, HD, 0);
    gather_kernel<true><<<gaGrid, 256, 0, stream>>>(off, cnt, csr_idx, csr_w, dinv, hb, conv_b + HD, nullptr, feat, FSTR);

    // chemistry features -> feat[:,128:256]
    feat_mfma_kernel<24, true><<<mmGrid, 256, 0, stream>>>(chemistry, wcf, chem_b, smiles_mask, feat, FSTR, HD);

    // decode pos+neg fused
    decode_mfma_kernel<<<2 * (NEP / 64), 256, 0, stream>>>(pos_edge, neg_edge, feat, w1f,
                                                           dec_b1, dec_w2, dec_b2, out);
}